// Round 1
// baseline (486.594 us; speedup 1.0000x reference)
//
#include <hip/hip_runtime.h>

typedef short v8s __attribute__((ext_vector_type(8)));
typedef float v4f __attribute__((ext_vector_type(4)));

__device__ __forceinline__ unsigned rne_hi(float f) {
    // bf16 round-to-nearest-even, result in top 16 bits
    unsigned u = __float_as_uint(f);
    return u + 0x7FFFu + ((u >> 16) & 1u);
}

// ---------------------------------------------------------------------------
// Pre-pass: X (B=64, C=128, H=32, W=32) fp32  ->  Xt (C, HW=1024, B=64) bf16
// Makes main-kernel A-staging loads contiguous along b.
// ---------------------------------------------------------------------------
__global__ __launch_bounds__(256) void xpose_kernel(const float* __restrict__ X,
                                                    unsigned short* __restrict__ Xt) {
    __shared__ float tile[64][65];
    const int bx  = blockIdx.x;      // 0..2047
    const int c   = bx >> 4;         // 0..127
    const int hw0 = (bx & 15) << 6;  // 0..960
    const int t    = threadIdx.x;
    const int lane = t & 63;
    const int brow = t >> 6;         // 0..3

#pragma unroll
    for (int r = 0; r < 16; ++r) {
        int b = brow + (r << 2);
        tile[b][lane] = X[((size_t)(b * 128 + c) << 10) + hw0 + lane];
    }
    __syncthreads();
#pragma unroll
    for (int r = 0; r < 16; ++r) {
        int row = brow + (r << 2);
        float f = tile[lane][row];
        Xt[(((size_t)c << 10) + hw0 + row << 6) + lane] =
            (unsigned short)(rne_hi(f) >> 16);
    }
}

// ---------------------------------------------------------------------------
// Main: one block per spatial location s. 64x64 output tile, K=1152, BK=32.
// 4 waves, each wave owns a 16-row m-strip, 4 n-tiles of 16x16x32 bf16 MFMA.
// ---------------------------------------------------------------------------
__global__ __launch_bounds__(256, 4) void vconv_kernel(
    const float* __restrict__ Wg,            // (1024, 1152, 64) fp32
    const float* __restrict__ bias,          // (1024) fp32
    const unsigned short* __restrict__ Xt,   // (128, 1024, 64) bf16
    float* __restrict__ out)                 // (64, 64, 1024) fp32
{
    // XOR-swizzled LDS: phys dword = row*16 + ((k>>3 ^ ((row>>2)&3))<<2) + ((k&7)>>1)
    __shared__ __align__(16) unsigned A_lds[64 * 16];
    __shared__ __align__(16) unsigned B_lds[64 * 16];
    __shared__ int tab[1152];
    __shared__ float csum[16][64];
    __shared__ float csum_tot[64];

    const int s = blockIdx.x;
    const int y = s >> 5, x = s & 31;
    const int t    = threadIdx.x;
    const int lane = t & 63;
    const int wv   = t >> 6;     // wave id 0..3

    // ---- per-block unfold offset table: k -> byte offset in Xt (or -1 if OOB)
    for (int k = t; k < 1152; k += 256) {
        int c  = k / 9;
        int r  = k - c * 9;
        int di = r / 3, dj = r - di * 3;
        int yy = y + di - 1, xx = x + dj - 1;
        int off = (((c << 10) + (yy << 5) + xx) << 7);  // *64 b *2 bytes
        bool ok = (yy >= 0) && (yy < 32) && (xx >= 0) && (xx < 32);
        tab[k] = ok ? off : -1;
    }

    const float bias_s = bias[s];

    // ---- staging roles: g16 selects 4 consecutive rows (b or c), hi4 selects k-pair
    const int g16 = t & 15;     // 0..15
    const int hi4 = t >> 4;     // 0..15
    const int r4  = g16 << 2;   // row base (b4 for A, c4 for B)

    // weight base for this thread: rows k = kk*32 + hi4*2 (+1), cols r4..r4+3
    const float* wbase = Wg + ((size_t)s * 1152 + (hi4 << 1)) * 64 + r4;

    // LDS write addresses (identical math for A and B): k = hi4*2
    unsigned waddr[4];
#pragma unroll
    for (int i = 0; i < 4; ++i) {
        int row = r4 + i;
        unsigned grp = (unsigned)((hi4 >> 2) ^ ((row >> 2) & 3));
        waddr[i] = (unsigned)(row << 4) + (grp << 2) + (unsigned)(hi4 & 3);
    }

    // ---- fragment read addresses
    const int quad = lane >> 4;
    const int mrow = (wv << 4) + (lane & 15);
    const unsigned a_raddr = (unsigned)(mrow << 4) + ((unsigned)(quad ^ ((mrow >> 2) & 3)) << 2);
    unsigned b_raddr[4];
#pragma unroll
    for (int t0 = 0; t0 < 4; ++t0) {
        int n = (t0 << 4) + (lane & 15);
        b_raddr[t0] = (unsigned)(n << 4) + ((unsigned)(quad ^ ((n >> 2) & 3)) << 2);
    }

    v4f acc[4];
#pragma unroll
    for (int t0 = 0; t0 < 4; ++t0) acc[t0] = (v4f){0.f, 0.f, 0.f, 0.f};
    float cs0 = 0.f, cs1 = 0.f, cs2 = 0.f, cs3 = 0.f;

    __syncthreads();  // tab ready

    for (int kk = 0; kk < 36; ++kk) {
        // ---- global loads (issue early)
        const float4 F0 = *(const float4*)(wbase + (size_t)kk * 2048);
        const float4 F1 = *(const float4*)(wbase + (size_t)kk * 2048 + 64);

        int k0 = (kk << 5) + (hi4 << 1);
        int o0 = tab[k0];
        int o1 = tab[k0 + 1];
        const char* xb = (const char*)Xt + (r4 << 1);
        uint2 P = *(const uint2*)(xb + (o0 >= 0 ? o0 : 0));
        uint2 Q = *(const uint2*)(xb + (o1 >= 0 ? o1 : 0));
        unsigned m0 = o0 >= 0 ? 0xFFFFFFFFu : 0u;
        unsigned m1 = o1 >= 0 ? 0xFFFFFFFFu : 0u;
        P.x &= m0; P.y &= m0; Q.x &= m1; Q.y &= m1;

        __syncthreads();  // previous iteration's fragment reads complete

        // ---- stage B (fp32 -> bf16 pairs, k even in lo, k odd in hi)
        B_lds[waddr[0]] = (rne_hi(F0.x) >> 16) | (rne_hi(F1.x) & 0xFFFF0000u);
        B_lds[waddr[1]] = (rne_hi(F0.y) >> 16) | (rne_hi(F1.y) & 0xFFFF0000u);
        B_lds[waddr[2]] = (rne_hi(F0.z) >> 16) | (rne_hi(F1.z) & 0xFFFF0000u);
        B_lds[waddr[3]] = (rne_hi(F0.w) >> 16) | (rne_hi(F1.w) & 0xFFFF0000u);
        cs0 += F0.x + F1.x;
        cs1 += F0.y + F1.y;
        cs2 += F0.z + F1.z;
        cs3 += F0.w + F1.w;

        // ---- stage A (already bf16; 4b x 2k register transpose)
        A_lds[waddr[0]] = (P.x & 0xFFFFu) | (Q.x << 16);
        A_lds[waddr[1]] = (P.x >> 16)     | (Q.x & 0xFFFF0000u);
        A_lds[waddr[2]] = (P.y & 0xFFFFu) | (Q.y << 16);
        A_lds[waddr[3]] = (P.y >> 16)     | (Q.y & 0xFFFF0000u);

        __syncthreads();

        // ---- fragments + MFMA
        v8s a = *(const v8s*)&A_lds[a_raddr];
        v8s b0 = *(const v8s*)&B_lds[b_raddr[0]];
        v8s b1 = *(const v8s*)&B_lds[b_raddr[1]];
        v8s b2 = *(const v8s*)&B_lds[b_raddr[2]];
        v8s b3 = *(const v8s*)&B_lds[b_raddr[3]];
        acc[0] = __builtin_amdgcn_mfma_f32_16x16x32_bf16(a, b0, acc[0], 0, 0, 0);
        acc[1] = __builtin_amdgcn_mfma_f32_16x16x32_bf16(a, b1, acc[1], 0, 0, 0);
        acc[2] = __builtin_amdgcn_mfma_f32_16x16x32_bf16(a, b2, acc[2], 0, 0, 0);
        acc[3] = __builtin_amdgcn_mfma_f32_16x16x32_bf16(a, b3, acc[3], 0, 0, 0);
    }

    // ---- column-sum reduction for the bias term
    csum[hi4][r4 + 0] = cs0;
    csum[hi4][r4 + 1] = cs1;
    csum[hi4][r4 + 2] = cs2;
    csum[hi4][r4 + 3] = cs3;
    __syncthreads();
    if (t < 64) {
        float tot = 0.f;
#pragma unroll
        for (int p = 0; p < 16; ++p) tot += csum[p][t];
        csum_tot[t] = tot;
    }
    __syncthreads();

    // ---- epilogue: D[m][n], n = lane&15 (+16*t0), m = wv*16 + quad*4 + r
#pragma unroll
    for (int t0 = 0; t0 < 4; ++t0) {
        int n = (t0 << 4) + (lane & 15);
        float cb = bias_s * csum_tot[n];
#pragma unroll
        for (int r = 0; r < 4; ++r) {
            int b = (wv << 4) + (quad << 2) + r;
            out[((size_t)(b * 64 + n) << 10) + s] = acc[t0][r] + cb;
        }
    }
}

// ---------------------------------------------------------------------------
extern "C" void kernel_launch(void* const* d_in, const int* in_sizes, int n_in,
                              void* d_out, int out_size, void* d_ws, size_t ws_size,
                              hipStream_t stream) {
    const float* X    = (const float*)d_in[0];  // (64,128,32,32)
    const float* Wg   = (const float*)d_in[1];  // (1024,1152,64)
    const float* bias = (const float*)d_in[2];  // (32,32)
    float* out = (float*)d_out;                 // (64,64,32,32)
    unsigned short* Xt = (unsigned short*)d_ws; // 16.78 MB bf16 scratch

    xpose_kernel<<<2048, 256, 0, stream>>>(X, Xt);
    vconv_kernel<<<1024, 256, 0, stream>>>(Wg, bias, Xt, out);
}

// Round 2
// 438.614 us; speedup vs baseline: 1.1094x; 1.1094x over previous
//
#include <hip/hip_runtime.h>

typedef short v8s __attribute__((ext_vector_type(8)));
typedef float v4f __attribute__((ext_vector_type(4)));

__device__ __forceinline__ unsigned rne_hi(float f) {
    unsigned u = __float_as_uint(f);
    return u + 0x7FFFu + ((u >> 16) & 1u);
}

#if defined(__has_builtin)
#if __has_builtin(__builtin_amdgcn_cvt_pk_bf16_f32)
#define HAVE_PK_BF16 1
#endif
#endif

__device__ __forceinline__ unsigned pk_bf16(float lo, float hi) {
#ifdef HAVE_PK_BF16
    auto r = __builtin_amdgcn_cvt_pk_bf16_f32(lo, hi);
    unsigned u;
    __builtin_memcpy(&u, &r, 4);
    return u;
#else
    return (rne_hi(lo) >> 16) | (rne_hi(hi) & 0xFFFF0000u);
#endif
}

__device__ __forceinline__ void barrier_raw() {
    asm volatile("s_barrier" ::: "memory");
}
__device__ __forceinline__ void barrier_lgkm() {
    asm volatile("s_waitcnt lgkmcnt(0)\n\ts_barrier" ::: "memory");
}

// ---------------------------------------------------------------------------
// Pre-pass: X (B=64, C=128, 32, 32) fp32 -> Xt (C, HW, B) bf16, plus a 256 B
// zero page at element 8388608 (OOB unfold taps land there -> no masking).
// ---------------------------------------------------------------------------
__global__ __launch_bounds__(256) void xpose_kernel(const float* __restrict__ X,
                                                    unsigned short* __restrict__ Xt) {
    __shared__ float tile[64][65];
    const int bx  = blockIdx.x;      // 0..2047
    const int c   = bx >> 4;
    const int hw0 = (bx & 15) << 6;
    const int t    = threadIdx.x;
    const int lane = t & 63;
    const int brow = t >> 6;

    if (bx == 0 && t < 128) Xt[8388608 + t] = 0;  // zero page

#pragma unroll
    for (int r = 0; r < 16; ++r) {
        int b = brow + (r << 2);
        tile[b][lane] = X[((size_t)(b * 128 + c) << 10) + hw0 + lane];
    }
    __syncthreads();
#pragma unroll
    for (int r = 0; r < 16; ++r) {
        int row = brow + (r << 2);
        float f = tile[lane][row];
        Xt[((((size_t)c << 10) + hw0 + row) << 6) + lane] =
            (unsigned short)(rne_hi(f) >> 16);
    }
}

// ---------------------------------------------------------------------------
// Main: one block per location s. 64x64 tile, K=1152, BK=64 (2 x BK=32 sub-
// tiles). 4 waves in 2x2 arrangement (each 32m x 32n). Register-prefetched
// weight/X loads; raw barriers (no vmcnt drain). Writes contiguous scratch.
// ---------------------------------------------------------------------------
__global__ __launch_bounds__(256, 4) void vconv_kernel(
    const float* __restrict__ Wg,            // (1024, 1152, 64) fp32
    const float* __restrict__ bias,          // (1024) fp32
    const unsigned short* __restrict__ Xt,   // (128, 1024, 64) bf16 + zero page
    float* __restrict__ scratch)             // (1024, 4096) fp32, s-major
{
    __shared__ __align__(16) unsigned A_lds[2][1024];
    __shared__ __align__(16) unsigned B_lds[2][1024];
    __shared__ int tab[1152];
    __shared__ float csum[16][65];
    __shared__ float csum_tot[64];

    const int s = blockIdx.x;
    const int y = s >> 5, x = s & 31;
    const int t    = threadIdx.x;
    const int lane = t & 63;
    const int wv   = t >> 6;
    const int mh   = wv >> 1, nh = wv & 1;

    // unfold table: k -> byte offset in Xt (OOB -> zero page at 16777216)
    for (int k = t; k < 1152; k += 256) {
        int c  = k / 9;
        int r  = k - c * 9;
        int di = r / 3, dj = r - di * 3;
        int yy = y + di - 1, xx = x + dj - 1;
        int off = ((c << 10) + (yy << 5) + xx) << 7;
        bool ok = (yy >= 0) && (yy < 32) && (xx >= 0) && (xx < 32);
        tab[k] = ok ? off : 16777216;
    }

    const float bias_s = bias[s];

    const int g16 = t & 15;
    const int hi4 = t >> 4;
    const int r4  = g16 << 2;

    const float* wbase = Wg + ((size_t)s * 1152 + (hi4 << 1)) * 64 + r4;
    const char*  xb    = (const char*)Xt + (r4 << 1);

    unsigned waddr[4];
#pragma unroll
    for (int i = 0; i < 4; ++i) {
        int row = r4 + i;
        unsigned grp = (unsigned)((hi4 >> 2) ^ ((row >> 2) & 3));
        waddr[i] = (unsigned)(row << 4) + (grp << 2) + (unsigned)(hi4 & 3);
    }

    const int quad = lane >> 4, l15 = lane & 15;
    unsigned a_raddr[2], b_raddr[2];
#pragma unroll
    for (int i = 0; i < 2; ++i) {
        int ra = (((mh << 1) + i) << 4) + l15;
        a_raddr[i] = (unsigned)(ra << 4) + ((unsigned)(quad ^ ((ra >> 2) & 3)) << 2);
        int rb = (((nh << 1) + i) << 4) + l15;
        b_raddr[i] = (unsigned)(rb << 4) + ((unsigned)(quad ^ ((rb >> 2) & 3)) << 2);
    }

    v4f acc[2][2];
#pragma unroll
    for (int i = 0; i < 2; ++i)
#pragma unroll
        for (int j = 0; j < 2; ++j) acc[i][j] = (v4f){0.f, 0.f, 0.f, 0.f};
    float cs0 = 0.f, cs1 = 0.f, cs2 = 0.f, cs3 = 0.f;

    barrier_lgkm();  // tab visible

    float4 Fa0, Fb0, Fa1, Fb1;
    uint2  P0, Q0, P1, Q1;

    auto LOAD = [&](int kk2) {
        const float* wb = wbase + (size_t)kk2 * 4096;
        Fa0 = *(const float4*)(wb);
        Fb0 = *(const float4*)(wb + 64);
        Fa1 = *(const float4*)(wb + 2048);
        Fb1 = *(const float4*)(wb + 2112);
        int kb  = (kk2 << 6) + (hi4 << 1);
        int o00 = tab[kb], o01 = tab[kb + 1];
        int o10 = tab[kb + 32], o11 = tab[kb + 33];
        P0 = *(const uint2*)(xb + o00);
        Q0 = *(const uint2*)(xb + o01);
        P1 = *(const uint2*)(xb + o10);
        Q1 = *(const uint2*)(xb + o11);
    };

    LOAD(0);

    for (int kk = 0; kk < 18; ++kk) {
        barrier_raw();  // prev fragment reads are drained (consumed by MFMA issue)

        // ---- stage sub-tile h=0
        B_lds[0][waddr[0]] = pk_bf16(Fa0.x, Fb0.x);
        B_lds[0][waddr[1]] = pk_bf16(Fa0.y, Fb0.y);
        B_lds[0][waddr[2]] = pk_bf16(Fa0.z, Fb0.z);
        B_lds[0][waddr[3]] = pk_bf16(Fa0.w, Fb0.w);
        A_lds[0][waddr[0]] = __builtin_amdgcn_perm(Q0.x, P0.x, 0x05040100u);
        A_lds[0][waddr[1]] = __builtin_amdgcn_perm(Q0.x, P0.x, 0x07060302u);
        A_lds[0][waddr[2]] = __builtin_amdgcn_perm(Q0.y, P0.y, 0x05040100u);
        A_lds[0][waddr[3]] = __builtin_amdgcn_perm(Q0.y, P0.y, 0x07060302u);
        // ---- stage sub-tile h=1
        B_lds[1][waddr[0]] = pk_bf16(Fa1.x, Fb1.x);
        B_lds[1][waddr[1]] = pk_bf16(Fa1.y, Fb1.y);
        B_lds[1][waddr[2]] = pk_bf16(Fa1.z, Fb1.z);
        B_lds[1][waddr[3]] = pk_bf16(Fa1.w, Fb1.w);
        A_lds[1][waddr[0]] = __builtin_amdgcn_perm(Q1.x, P1.x, 0x05040100u);
        A_lds[1][waddr[1]] = __builtin_amdgcn_perm(Q1.x, P1.x, 0x07060302u);
        A_lds[1][waddr[2]] = __builtin_amdgcn_perm(Q1.y, P1.y, 0x05040100u);
        A_lds[1][waddr[3]] = __builtin_amdgcn_perm(Q1.y, P1.y, 0x07060302u);

        cs0 += (Fa0.x + Fb0.x) + (Fa1.x + Fb1.x);
        cs1 += (Fa0.y + Fb0.y) + (Fa1.y + Fb1.y);
        cs2 += (Fa0.z + Fb0.z) + (Fa1.z + Fb1.z);
        cs3 += (Fa0.w + Fb0.w) + (Fa1.w + Fb1.w);

        if (kk < 17) LOAD(kk + 1);  // in flight across MFMA phase + barrier

        barrier_lgkm();  // drain my ds_writes; vmcnt NOT drained

#pragma unroll
        for (int h = 0; h < 2; ++h) {
            v8s a0 = *(const v8s*)&A_lds[h][a_raddr[0]];
            v8s a1 = *(const v8s*)&A_lds[h][a_raddr[1]];
            v8s b0 = *(const v8s*)&B_lds[h][b_raddr[0]];
            v8s b1 = *(const v8s*)&B_lds[h][b_raddr[1]];
            acc[0][0] = __builtin_amdgcn_mfma_f32_16x16x32_bf16(a0, b0, acc[0][0], 0, 0, 0);
            acc[0][1] = __builtin_amdgcn_mfma_f32_16x16x32_bf16(a0, b1, acc[0][1], 0, 0, 0);
            acc[1][0] = __builtin_amdgcn_mfma_f32_16x16x32_bf16(a1, b0, acc[1][0], 0, 0, 0);
            acc[1][1] = __builtin_amdgcn_mfma_f32_16x16x32_bf16(a1, b1, acc[1][1], 0, 0, 0);
        }
    }

    // ---- bias * column-sum term
    csum[hi4][r4 + 0] = cs0;
    csum[hi4][r4 + 1] = cs1;
    csum[hi4][r4 + 2] = cs2;
    csum[hi4][r4 + 3] = cs3;
    barrier_lgkm();
    if (t < 64) {
        float tot = 0.f;
#pragma unroll
        for (int p = 0; p < 16; ++p) tot += csum[p][t];
        csum_tot[t] = tot;
    }
    barrier_lgkm();

    // ---- epilogue: contiguous (s, m) scratch writes (full 64 B lines)
    float* sb = scratch + ((size_t)s << 12);
#pragma unroll
    for (int j = 0; j < 2; ++j) {
        int n = (((nh << 1) + j) << 4) + l15;
        float cb = bias_s * csum_tot[n];
#pragma unroll
        for (int i = 0; i < 2; ++i) {
#pragma unroll
            for (int r = 0; r < 4; ++r) {
                int m = (((mh << 1) + i) << 4) + (quad << 2) + r;
                sb[(m << 6) + n] = acc[i][j][r] + cb;
            }
        }
    }
}

// ---------------------------------------------------------------------------
// scratch (s, mm) -> out (mm, s), mm = b*64 + c. 64x64 fp32 tile transpose.
// ---------------------------------------------------------------------------
__global__ __launch_bounds__(256) void otrans_kernel(const float* __restrict__ S,
                                                     float* __restrict__ out) {
    __shared__ float tile[64][65];
    const int bx = blockIdx.x;       // 0..1023
    const int m0 = (bx & 63) << 6;
    const int s0 = (bx >> 6) << 6;
    const int t = threadIdx.x, lane = t & 63, brow = t >> 6;
#pragma unroll
    for (int r = 0; r < 16; ++r) {
        int row = brow + (r << 2);
        tile[row][lane] = S[((size_t)(s0 + row) << 12) + m0 + lane];
    }
    __syncthreads();
#pragma unroll
    for (int r = 0; r < 16; ++r) {
        int row = brow + (r << 2);
        out[((size_t)(m0 + row) << 10) + s0 + lane] = tile[lane][row];
    }
}

// ---------------------------------------------------------------------------
extern "C" void kernel_launch(void* const* d_in, const int* in_sizes, int n_in,
                              void* d_out, int out_size, void* d_ws, size_t ws_size,
                              hipStream_t stream) {
    const float* X    = (const float*)d_in[0];  // (64,128,32,32)
    const float* Wg   = (const float*)d_in[1];  // (1024,1152,64)
    const float* bias = (const float*)d_in[2];  // (32,32)
    float* out = (float*)d_out;                 // (64,64,32,32)

    unsigned short* Xt = (unsigned short*)d_ws;                    // 16 MB + zero page
    float* scratch = (float*)((char*)d_ws + 16777472);             // (1024,4096) fp32

    xpose_kernel<<<2048, 256, 0, stream>>>(X, Xt);
    vconv_kernel<<<1024, 256, 0, stream>>>(Wg, bias, Xt, scratch);
    otrans_kernel<<<1024, 256, 0, stream>>>(scratch, out);
}

// Round 4
// 414.403 us; speedup vs baseline: 1.1742x; 1.0584x over previous
//
#include <hip/hip_runtime.h>

typedef short v8s __attribute__((ext_vector_type(8)));
typedef float v4f __attribute__((ext_vector_type(4)));

__device__ __forceinline__ unsigned rne_hi(float f) {
    unsigned u = __float_as_uint(f);
    return u + 0x7FFFu + ((u >> 16) & 1u);
}

#if defined(__has_builtin)
#if __has_builtin(__builtin_amdgcn_cvt_pk_bf16_f32)
#define HAVE_PK_BF16 1
#endif
#endif

__device__ __forceinline__ unsigned pk_bf16(float lo, float hi) {
#ifdef HAVE_PK_BF16
    auto r = __builtin_amdgcn_cvt_pk_bf16_f32(lo, hi);
    unsigned u;
    __builtin_memcpy(&u, &r, 4);
    return u;
#else
    return (rne_hi(lo) >> 16) | (rne_hi(hi) & 0xFFFF0000u);
#endif
}

__device__ __forceinline__ void barrier_raw() {
    asm volatile("s_barrier" ::: "memory");
}
__device__ __forceinline__ void barrier_lgkm() {
    asm volatile("s_waitcnt lgkmcnt(0)\n\ts_barrier" ::: "memory");
}

// ---------------------------------------------------------------------------
// Pre-pass: X (B=64, C=128, 32, 32) fp32 -> Xt (C, HW, B) bf16, plus a 256 B
// zero page at element 8388608 (OOB unfold taps land there -> no masking).
// ---------------------------------------------------------------------------
__global__ __launch_bounds__(256) void xpose_kernel(const float* __restrict__ X,
                                                    unsigned short* __restrict__ Xt) {
    __shared__ float tile[64][65];
    const int bx  = blockIdx.x;      // 0..2047
    const int c   = bx >> 4;
    const int hw0 = (bx & 15) << 6;
    const int t    = threadIdx.x;
    const int lane = t & 63;
    const int brow = t >> 6;

    if (bx == 0 && t < 128) Xt[8388608 + t] = 0;  // zero page

#pragma unroll
    for (int r = 0; r < 16; ++r) {
        int b = brow + (r << 2);
        tile[b][lane] = __builtin_nontemporal_load(
            &X[((size_t)(b * 128 + c) << 10) + hw0 + lane]);
    }
    __syncthreads();
#pragma unroll
    for (int r = 0; r < 16; ++r) {
        int row = brow + (r << 2);
        float f = tile[lane][row];
        Xt[((((size_t)c << 10) + hw0 + row) << 6) + lane] =
            (unsigned short)(rne_hi(f) >> 16);
    }
}

// ---------------------------------------------------------------------------
// Main: one block per location s. 64x64 tile, K=1152, BK=64 (2 x BK=32 sub-
// tiles). 4 waves in 2x2 arrangement (each 32m x 32n). Register-prefetched
// weight/X loads; raw barriers (no vmcnt drain). Writes bf16 scratch (s, mm).
// ---------------------------------------------------------------------------
__global__ __launch_bounds__(256, 4) void vconv_kernel(
    const float* __restrict__ Wg,            // (1024, 1152, 64) fp32
    const float* __restrict__ bias,          // (1024) fp32
    const unsigned short* __restrict__ Xt,   // (128, 1024, 64) bf16 + zero page
    unsigned short* __restrict__ scratch)    // (1024, 4096) bf16, s-major
{
    __shared__ __align__(16) unsigned A_lds[2][1024];
    __shared__ __align__(16) unsigned B_lds[2][1024];
    __shared__ int tab[1152];
    __shared__ float csum[16][65];
    __shared__ float csum_tot[64];

    const int s = blockIdx.x;
    const int y = s >> 5, x = s & 31;
    const int t    = threadIdx.x;
    const int lane = t & 63;
    const int wv   = t >> 6;
    const int mh   = wv >> 1, nh = wv & 1;

    // unfold table: k -> byte offset in Xt (OOB -> zero page at 16777216)
    for (int k = t; k < 1152; k += 256) {
        int c  = k / 9;
        int r  = k - c * 9;
        int di = r / 3, dj = r - di * 3;
        int yy = y + di - 1, xx = x + dj - 1;
        int off = ((c << 10) + (yy << 5) + xx) << 7;
        bool ok = (yy >= 0) && (yy < 32) && (xx >= 0) && (xx < 32);
        tab[k] = ok ? off : 16777216;
    }

    const float bias_s = bias[s];

    const int g16 = t & 15;
    const int hi4 = t >> 4;
    const int r4  = g16 << 2;

    const float* wbase = Wg + ((size_t)s * 1152 + (hi4 << 1)) * 64 + r4;
    const char*  xb    = (const char*)Xt + (r4 << 1);

    unsigned waddr[4];
#pragma unroll
    for (int i = 0; i < 4; ++i) {
        int row = r4 + i;
        unsigned grp = (unsigned)((hi4 >> 2) ^ ((row >> 2) & 3));
        waddr[i] = (unsigned)(row << 4) + (grp << 2) + (unsigned)(hi4 & 3);
    }

    const int quad = lane >> 4, l15 = lane & 15;
    unsigned a_raddr[2], b_raddr[2];
#pragma unroll
    for (int i = 0; i < 2; ++i) {
        int ra = (((mh << 1) + i) << 4) + l15;
        a_raddr[i] = (unsigned)(ra << 4) + ((unsigned)(quad ^ ((ra >> 2) & 3)) << 2);
        int rb = (((nh << 1) + i) << 4) + l15;
        b_raddr[i] = (unsigned)(rb << 4) + ((unsigned)(quad ^ ((rb >> 2) & 3)) << 2);
    }

    v4f acc[2][2];
#pragma unroll
    for (int i = 0; i < 2; ++i)
#pragma unroll
        for (int j = 0; j < 2; ++j) acc[i][j] = (v4f){0.f, 0.f, 0.f, 0.f};
    float cs0 = 0.f, cs1 = 0.f, cs2 = 0.f, cs3 = 0.f;

    barrier_lgkm();  // tab visible

    v4f Fa0, Fb0, Fa1, Fb1;
    uint2  P0, Q0, P1, Q1;

    auto LOAD = [&](int kk2) {
        const v4f* wb = (const v4f*)(wbase + (size_t)kk2 * 4096);
        Fa0 = __builtin_nontemporal_load(wb);
        Fb0 = __builtin_nontemporal_load(wb + 16);        // +64 floats
        Fa1 = __builtin_nontemporal_load(wb + 512);       // +2048 floats
        Fb1 = __builtin_nontemporal_load(wb + 528);       // +2112 floats
        int kb  = (kk2 << 6) + (hi4 << 1);
        int o00 = tab[kb], o01 = tab[kb + 1];
        int o10 = tab[kb + 32], o11 = tab[kb + 33];
        P0 = *(const uint2*)(xb + o00);
        Q0 = *(const uint2*)(xb + o01);
        P1 = *(const uint2*)(xb + o10);
        Q1 = *(const uint2*)(xb + o11);
    };

    LOAD(0);

    for (int kk = 0; kk < 18; ++kk) {
        barrier_raw();  // prev fragment reads already consumed by MFMA issue

        // ---- stage sub-tile h=0
        B_lds[0][waddr[0]] = pk_bf16(Fa0.x, Fb0.x);
        B_lds[0][waddr[1]] = pk_bf16(Fa0.y, Fb0.y);
        B_lds[0][waddr[2]] = pk_bf16(Fa0.z, Fb0.z);
        B_lds[0][waddr[3]] = pk_bf16(Fa0.w, Fb0.w);
        A_lds[0][waddr[0]] = __builtin_amdgcn_perm(Q0.x, P0.x, 0x05040100u);
        A_lds[0][waddr[1]] = __builtin_amdgcn_perm(Q0.x, P0.x, 0x07060302u);
        A_lds[0][waddr[2]] = __builtin_amdgcn_perm(Q0.y, P0.y, 0x05040100u);
        A_lds[0][waddr[3]] = __builtin_amdgcn_perm(Q0.y, P0.y, 0x07060302u);
        // ---- stage sub-tile h=1
        B_lds[1][waddr[0]] = pk_bf16(Fa1.x, Fb1.x);
        B_lds[1][waddr[1]] = pk_bf16(Fa1.y, Fb1.y);
        B_lds[1][waddr[2]] = pk_bf16(Fa1.z, Fb1.z);
        B_lds[1][waddr[3]] = pk_bf16(Fa1.w, Fb1.w);
        A_lds[1][waddr[0]] = __builtin_amdgcn_perm(Q1.x, P1.x, 0x05040100u);
        A_lds[1][waddr[1]] = __builtin_amdgcn_perm(Q1.x, P1.x, 0x07060302u);
        A_lds[1][waddr[2]] = __builtin_amdgcn_perm(Q1.y, P1.y, 0x05040100u);
        A_lds[1][waddr[3]] = __builtin_amdgcn_perm(Q1.y, P1.y, 0x07060302u);

        cs0 += (Fa0.x + Fb0.x) + (Fa1.x + Fb1.x);
        cs1 += (Fa0.y + Fb0.y) + (Fa1.y + Fb1.y);
        cs2 += (Fa0.z + Fb0.z) + (Fa1.z + Fb1.z);
        cs3 += (Fa0.w + Fb0.w) + (Fa1.w + Fb1.w);

        if (kk < 17) LOAD(kk + 1);  // stays in flight across MFMA phase + barrier

        barrier_lgkm();  // drain my ds_writes; vmcnt NOT drained

#pragma unroll
        for (int h = 0; h < 2; ++h) {
            v8s a0 = *(const v8s*)&A_lds[h][a_raddr[0]];
            v8s a1 = *(const v8s*)&A_lds[h][a_raddr[1]];
            v8s b0 = *(const v8s*)&B_lds[h][b_raddr[0]];
            v8s b1 = *(const v8s*)&B_lds[h][b_raddr[1]];
            acc[0][0] = __builtin_amdgcn_mfma_f32_16x16x32_bf16(a0, b0, acc[0][0], 0, 0, 0);
            acc[0][1] = __builtin_amdgcn_mfma_f32_16x16x32_bf16(a0, b1, acc[0][1], 0, 0, 0);
            acc[1][0] = __builtin_amdgcn_mfma_f32_16x16x32_bf16(a1, b0, acc[1][0], 0, 0, 0);
            acc[1][1] = __builtin_amdgcn_mfma_f32_16x16x32_bf16(a1, b1, acc[1][1], 0, 0, 0);
        }
    }

    // ---- bias * column-sum term
    csum[hi4][r4 + 0] = cs0;
    csum[hi4][r4 + 1] = cs1;
    csum[hi4][r4 + 2] = cs2;
    csum[hi4][r4 + 3] = cs3;
    barrier_lgkm();
    if (t < 64) {
        float tot = 0.f;
#pragma unroll
        for (int p = 0; p < 16; ++p) tot += csum[p][t];
        csum_tot[t] = tot;
    }
    barrier_lgkm();

    // ---- epilogue: contiguous (s, mm) bf16 scratch writes
    unsigned short* sb = scratch + ((size_t)s << 12);
#pragma unroll
    for (int j = 0; j < 2; ++j) {
        int n = (((nh << 1) + j) << 4) + l15;
        float cb = bias_s * csum_tot[n];
#pragma unroll
        for (int i = 0; i < 2; ++i) {
#pragma unroll
            for (int r = 0; r < 4; ++r) {
                int m = (((mh << 1) + i) << 4) + (quad << 2) + r;
                sb[(m << 6) + n] = (unsigned short)(rne_hi(acc[i][j][r] + cb) >> 16);
            }
        }
    }
}

// ---------------------------------------------------------------------------
// scratch (s, mm) bf16 -> out (mm, s) fp32, mm = b*64 + c. 64x64 transpose.
// ---------------------------------------------------------------------------
__global__ __launch_bounds__(256) void otrans_kernel(const unsigned short* __restrict__ S,
                                                     float* __restrict__ out) {
    __shared__ unsigned short tile[64][66];
    const int bx = blockIdx.x;       // 0..1023
    const int m0 = (bx & 63) << 6;
    const int s0 = (bx >> 6) << 6;
    const int t = threadIdx.x, lane = t & 63, brow = t >> 6;
#pragma unroll
    for (int r = 0; r < 16; ++r) {
        int row = brow + (r << 2);
        tile[row][lane] = S[((size_t)(s0 + row) << 12) + m0 + lane];
    }
    __syncthreads();
#pragma unroll
    for (int r = 0; r < 16; ++r) {
        int row = brow + (r << 2);
        float f = __uint_as_float((unsigned)tile[lane][row] << 16);
        __builtin_nontemporal_store(f, &out[((size_t)(m0 + row) << 10) + s0 + lane]);
    }
}

// ---------------------------------------------------------------------------
extern "C" void kernel_launch(void* const* d_in, const int* in_sizes, int n_in,
                              void* d_out, int out_size, void* d_ws, size_t ws_size,
                              hipStream_t stream) {
    const float* X    = (const float*)d_in[0];  // (64,128,32,32)
    const float* Wg   = (const float*)d_in[1];  // (1024,1152,64)
    const float* bias = (const float*)d_in[2];  // (32,32)
    float* out = (float*)d_out;                 // (64,64,32,32)

    unsigned short* Xt = (unsigned short*)d_ws;                    // 16 MB + zero page
    unsigned short* scratch = (unsigned short*)((char*)d_ws + 16777472);  // (1024,4096) bf16

    xpose_kernel<<<2048, 256, 0, stream>>>(X, Xt);
    vconv_kernel<<<1024, 256, 0, stream>>>(Wg, bias, Xt, scratch);
    otrans_kernel<<<1024, 256, 0, stream>>>(scratch, out);
}